// Round 8
// baseline (101.096 us; speedup 1.0000x reference)
//
#include <hip/hip_runtime.h>

// ROIAlign (FPN, multi-level) for MI355X.
// Inputs (f32): fm2 [4,256,256,256] s4 | fm3 [4,128,128,256] s8
//               fm4 [4,64,64,256] s16  | fm5 [4,32,32,256] s32
//               rois [4,512,4] (x1,y1,x2,y2)
// Output (f32): [4,512,256,7,7]
//
// R7 -> R8: cross-bin row reuse (bytes are the proven bottleneck).
// Wave = output column sx (7 waves, 448 threads/block, 1 ROI/block).
// Col quad (4 merged offsets/weights per sx) hoisted once per column.
// Per bin: R6-style batched scalar-guarded loads, plus a 2-deep cache of
// (row_id -> x-reduced row value xr) carried across the column's 7 bins:
// a cache hit skips that row's 3-4 pixel loads AND its x-reduction FMAs.
// FPN level assignment makes sample step ~1 -> adjacent bins share rows.

constexpr int S     = 7;
constexpr int SS    = 49;
constexpr int CCH   = 256;
constexpr int NROI  = 512;
constexpr int BATCH = 4;

__device__ __forceinline__ unsigned rflu(unsigned x) {
    return (unsigned)__builtin_amdgcn_readfirstlane((int)x);
}

__global__ __launch_bounds__(448) void roialign_kernel(
    const float* __restrict__ fm2, const float* __restrict__ fm3,
    const float* __restrict__ fm4, const float* __restrict__ fm5,
    const float* __restrict__ rois, float* __restrict__ out)
{
    __shared__ float    tile[SS * CCH];   // 50176 B, XOR-swizzled channel idx
    __shared__ float    s_wyh[14], s_wyl[14], s_wxh[14], s_wxl[14];
    __shared__ unsigned s_ry0[14], s_ry1[14], s_cx0[14], s_cx1[14];
    __shared__ float    s_rw[7][4];       // merged row weights per sy
    __shared__ unsigned s_rr[7][4];       // merged row byte-offsets per sy
    __shared__ unsigned s_rm[7];          // row survive mask per sy (bits 0-3)
    __shared__ float    s_cw[7][4];       // merged col weights per sx
    __shared__ unsigned s_cc[7][4];       // merged col byte-offsets per sx
    __shared__ unsigned s_cm[7];          // col survive mask per sx (bits 0-3)

    const int roi = blockIdx.x;           // 0 .. B*N-1
    const int b   = roi >> 9;

    // ---- wave-uniform prologue ----
    const float x1  = rois[roi * 4 + 0];
    const float y1v = rois[roi * 4 + 1];
    const float x2  = rois[roi * 4 + 2];
    const float y2v = rois[roi * 4 + 3];

    const float area = (y2v - y1v) * (x2 - x1);
    const float lraw = logf(sqrtf(area) * (1.0f / 224.0f)) * 1.4426950408889634f + 4.0f;
    int lvl = (int)rintf(lraw);
    lvl = lvl < 2 ? 2 : (lvl > 5 ? 5 : lvl);

    const float* fm; int H; float scale;
    if (lvl == 2)      { fm = fm2; H = 256; scale = 0.25f;    }
    else if (lvl == 3) { fm = fm3; H = 128; scale = 0.125f;   }
    else if (lvl == 4) { fm = fm4; H = 64;  scale = 0.0625f;  }
    else               { fm = fm5; H = 32;  scale = 0.03125f; }
    const int W = H;
    fm += (size_t)b * H * W * CCH;

    const float bx1 = x1 * scale, by1 = y1v * scale;
    const float rw  = fmaxf(x2 * scale - bx1, 1.0f);
    const float rh  = fmaxf(y2v * scale - by1, 1.0f);
    const float stx = rw * (1.0f / 7.0f);
    const float sty = rh * (1.0f / 7.0f);

    const int t = threadIdx.x;

    // ---- sample LUT: 14 y entries (wave 0) + 14 x entries (wave 1) ----
    if (t < 14) {
        const int k = t;
        const float yy = by1 + ((float)k + 0.5f) * 0.5f * sty;
        const float Hf = (float)H;
        const bool  v  = (yy > -1.0f) && (yy < Hf);
        const float yc = fminf(fmaxf(yy, 0.0f), Hf - 1.0f);
        const int   y0 = (int)floorf(yc);
        const int   y1i = min(y0 + 1, H - 1);
        const float ly = yc - (float)y0;
        s_wyl[k] = v ? ly : 0.0f;
        s_wyh[k] = v ? 1.0f - ly : 0.0f;
        s_ry0[k] = (unsigned)(y0  * W * (CCH * 4));   // byte offset of fm row
        s_ry1[k] = (unsigned)(y1i * W * (CCH * 4));
    } else if (t >= 64 && t < 78) {
        const int k = t - 64;
        const float xx = bx1 + ((float)k + 0.5f) * 0.5f * stx;
        const float Wf = (float)W;
        const bool  v  = (xx > -1.0f) && (xx < Wf);
        const float xc = fminf(fmaxf(xx, 0.0f), Wf - 1.0f);
        const int   x0 = (int)floorf(xc);
        const int   x1i = min(x0 + 1, W - 1);
        const float lx = xc - (float)x0;
        s_wxl[k] = v ? lx : 0.0f;
        s_wxh[k] = v ? 1.0f - lx : 0.0f;
        s_cx0[k] = (unsigned)(x0  * (CCH * 4));       // byte offset of fm col
        s_cx1[k] = (unsigned)(x1i * (CCH * 4));
    }
    __syncthreads();

    // ---- merged row data per sy (t<7) and col data per sx (64<=t<71) ----
    if (t < 7) {
        const int ky = t << 1;
        float w0 = s_wyh[ky], w1 = s_wyl[ky], w2 = s_wyh[ky + 1], w3 = s_wyl[ky + 1];
        const unsigned rA = s_ry0[ky], rB = s_ry1[ky];
        const unsigned rC = s_ry0[ky + 1], rD = s_ry1[ky + 1];
        {
            const bool eBA = (rB == rA);
            if (eBA) { w0 += w1; w1 = 0.f; }
            const bool eCA = (rC == rA);
            const bool eCB = !eCA && (rC == rB);
            if (eCA) w0 += w2; else if (eCB) w1 += w2;
            if (eCA || eCB) w2 = 0.f;
            const bool eDA = (rD == rA);
            const bool eDB = !eDA && (rD == rB);
            const bool eDC = !eDA && !eDB && (rD == rC);
            if (eDA) w0 += w3; else if (eDB) w1 += w3; else if (eDC) w2 += w3;
            if (eDA || eDB || eDC) w3 = 0.f;
        }
        s_rw[t][0] = w0; s_rw[t][1] = w1; s_rw[t][2] = w2; s_rw[t][3] = w3;
        s_rr[t][0] = rA; s_rr[t][1] = rB; s_rr[t][2] = rC; s_rr[t][3] = rD;
        s_rm[t] = (w0 != 0.f ? 1u : 0u) | (w1 != 0.f ? 2u : 0u)
                | (w2 != 0.f ? 4u : 0u) | (w3 != 0.f ? 8u : 0u);
    } else if (t >= 64 && t < 71) {
        const int sx = t - 64;
        const int kx = sx << 1;
        float u0 = s_wxh[kx], u1 = s_wxl[kx], u2 = s_wxh[kx + 1], u3 = s_wxl[kx + 1];
        const unsigned cA = s_cx0[kx], cB = s_cx1[kx];
        const unsigned cC = s_cx0[kx + 1], cD = s_cx1[kx + 1];
        {
            const bool eBA = (cB == cA);
            if (eBA) { u0 += u1; u1 = 0.f; }
            const bool eCA = (cC == cA);
            const bool eCB = !eCA && (cC == cB);
            if (eCA) u0 += u2; else if (eCB) u1 += u2;
            if (eCA || eCB) u2 = 0.f;
            const bool eDA = (cD == cA);
            const bool eDB = !eDA && (cD == cB);
            const bool eDC = !eDA && !eDB && (cD == cC);
            if (eDA) u0 += u3; else if (eDB) u1 += u3; else if (eDC) u2 += u3;
            if (eDA || eDB || eDC) u3 = 0.f;
        }
        s_cw[sx][0] = u0; s_cw[sx][1] = u1; s_cw[sx][2] = u2; s_cw[sx][3] = u3;
        s_cc[sx][0] = cA; s_cc[sx][1] = cB; s_cc[sx][2] = cC; s_cc[sx][3] = cD;
        s_cm[sx] = (u0 != 0.f ? 1u : 0u) | (u1 != 0.f ? 2u : 0u)
                 | (u2 != 0.f ? 4u : 0u) | (u3 != 0.f ? 8u : 0u);
    }
    __syncthreads();

    // ---- compute: wave = column sx; 7 bins down the column; 4 ch/lane ----
    const int lane = t & 63;
    const int wv   = t >> 6;                       // 0..6 = sx
    const unsigned cb = (unsigned)(lane << 4);     // byte offset within pixel
    const char* __restrict__ fmb = (const char*)fm;
    const float4 z4 = make_float4(0.f, 0.f, 0.f, 0.f);

    // column uniforms (hoisted once)
    const unsigned cmask = rflu(s_cm[wv]);
    const unsigned c0 = rflu(s_cc[wv][0]), c1 = rflu(s_cc[wv][1]);
    const unsigned c2 = rflu(s_cc[wv][2]), c3 = rflu(s_cc[wv][3]);
    const float u0 = s_cw[wv][0], u1 = s_cw[wv][1];
    const float u2 = s_cw[wv][2], u3 = s_cw[wv][3];

    // 2-deep (row_id -> xr) cache
    unsigned idA = 0xFFFFFFFFu, idB = 0xFFFFFFFFu;
    float4 xrA = z4, xrB = z4;

    // persistent pixel regs (zero-init once; stale-finite afterwards, always
    // multiplied by zero weights when not freshly loaded)
    float4 p00 = z4, p01 = z4, p02 = z4, p03 = z4;
    float4 p10 = z4, p11 = z4, p12 = z4, p13 = z4;
    float4 p20 = z4, p21 = z4, p22 = z4, p23 = z4;
    float4 p30 = z4, p31 = z4, p32 = z4, p33 = z4;

#define LD4(OFF) (*(const float4*)(fmb + (OFF)))
#define XR4(DST, P0, P1, P2, P3) \
    DST.x = fmaf(u0,(P0).x, fmaf(u1,(P1).x, fmaf(u2,(P2).x, u3*(P3).x))); \
    DST.y = fmaf(u0,(P0).y, fmaf(u1,(P1).y, fmaf(u2,(P2).y, u3*(P3).y))); \
    DST.z = fmaf(u0,(P0).z, fmaf(u1,(P1).z, fmaf(u2,(P2).z, u3*(P3).z))); \
    DST.w = fmaf(u0,(P0).w, fmaf(u1,(P1).w, fmaf(u2,(P2).w, u3*(P3).w)));

    #pragma unroll
    for (int sy = 0; sy < 7; ++sy) {
        const unsigned rmask = rflu(s_rm[sy]);
        const unsigned r0 = rflu(s_rr[sy][0]), r1 = rflu(s_rr[sy][1]);
        const unsigned r2 = rflu(s_rr[sy][2]), r3 = rflu(s_rr[sy][3]);
        const float w0 = s_rw[sy][0], w1 = s_rw[sy][1];
        const float w2 = s_rw[sy][2], w3 = s_rw[sy][3];

        // scalar hit/fresh flags
        const bool h0A = (r0 == idA), h0B = (r0 == idB);
        const bool h1A = (r1 == idA), h1B = (r1 == idB);
        const bool h2A = (r2 == idA), h2B = (r2 == idB);
        const bool h3A = (r3 == idA), h3B = (r3 == idB);
        const bool f0 = (rmask & 1u) && !h0A && !h0B;
        const bool f1 = (rmask & 2u) && !h1A && !h1B;
        const bool f2 = (rmask & 4u) && !h2A && !h2B;
        const bool f3 = (rmask & 8u) && !h3A && !h3B;

        // batched guarded loads (wave-uniform scalar guards)
        if (f0) {
            if (cmask & 1u) p00 = LD4(r0 + c0 + cb);
            if (cmask & 2u) p01 = LD4(r0 + c1 + cb);
            if (cmask & 4u) p02 = LD4(r0 + c2 + cb);
            if (cmask & 8u) p03 = LD4(r0 + c3 + cb);
        }
        if (f1) {
            if (cmask & 1u) p10 = LD4(r1 + c0 + cb);
            if (cmask & 2u) p11 = LD4(r1 + c1 + cb);
            if (cmask & 4u) p12 = LD4(r1 + c2 + cb);
            if (cmask & 8u) p13 = LD4(r1 + c3 + cb);
        }
        if (f2) {
            if (cmask & 1u) p20 = LD4(r2 + c0 + cb);
            if (cmask & 2u) p21 = LD4(r2 + c1 + cb);
            if (cmask & 4u) p22 = LD4(r2 + c2 + cb);
            if (cmask & 8u) p23 = LD4(r2 + c3 + cb);
        }
        if (f3) {
            if (cmask & 1u) p30 = LD4(r3 + c0 + cb);
            if (cmask & 2u) p31 = LD4(r3 + c1 + cb);
            if (cmask & 4u) p32 = LD4(r3 + c2 + cb);
            if (cmask & 8u) p33 = LD4(r3 + c3 + cb);
        }
        __builtin_amdgcn_sched_barrier(0);

        // x-reduced row values (cache hit or fresh reduction)
        float4 xr0, xr1, xr2, xr3;
        if (h0A) xr0 = xrA; else if (h0B) xr0 = xrB; else { XR4(xr0, p00, p01, p02, p03); }
        if (h1A) xr1 = xrA; else if (h1B) xr1 = xrB; else { XR4(xr1, p10, p11, p12, p13); }
        if (h2A) xr2 = xrA; else if (h2B) xr2 = xrB; else { XR4(xr2, p20, p21, p22, p23); }
        if (h3A) xr3 = xrA; else if (h3B) xr3 = xrB; else { XR4(xr3, p30, p31, p32, p33); }

        // y-reduction (masked slots have w == 0 and finite xr -> safe)
        float4 acc;
        acc.x = fmaf(w0, xr0.x, fmaf(w1, xr1.x, fmaf(w2, xr2.x, w3 * xr3.x)));
        acc.y = fmaf(w0, xr0.y, fmaf(w1, xr1.y, fmaf(w2, xr2.y, w3 * xr3.y)));
        acc.z = fmaf(w0, xr0.z, fmaf(w1, xr1.z, fmaf(w2, xr2.z, w3 * xr3.z)));
        acc.w = fmaf(w0, xr0.w, fmaf(w1, xr1.w, fmaf(w2, xr2.w, w3 * xr3.w)));

        // tile[bin][c], channel idx XOR-swizzled (R6 writeback pattern)
        const int bin = sy * 7 + wv;
        const unsigned xsw = (((unsigned)bin >> 2) & 7u) << 2;
        float* dst = &tile[bin * CCH + ((unsigned)(lane << 2) ^ xsw)];
        *(float4*)dst = make_float4(acc.x * 0.25f, acc.y * 0.25f,
                                    acc.z * 0.25f, acc.w * 0.25f);

        // cache update: shift in surviving slots ascending -> A = largest row
        if (rmask & 1u) { idB = idA; xrB = xrA; idA = r0; xrA = xr0; }
        if (rmask & 2u) { idB = idA; xrB = xrA; idA = r1; xrA = xr1; }
        if (rmask & 4u) { idB = idA; xrB = xrA; idA = r2; xrA = xr2; }
        if (rmask & 8u) { idB = idA; xrB = xrA; idA = r3; xrA = xr3; }
    }
#undef LD4
#undef XR4

    __syncthreads();

    // ---- writeback: contiguous 256*49 floats, coalesced float4 stores ----
    float* oreg = out + (size_t)roi * (CCH * SS);
    for (int i = t; i < (CCH * SS) / 4; i += 448) {
        const int f0i = i * 4;
        float4 v;
        {
            const int f = f0i + 0;
            const int c = f / SS, bn = f - c * SS;
            v.x = tile[bn * CCH + (c ^ ((((unsigned)bn >> 2) & 7u) << 2))];
        }
        {
            const int f = f0i + 1;
            const int c = f / SS, bn = f - c * SS;
            v.y = tile[bn * CCH + (c ^ ((((unsigned)bn >> 2) & 7u) << 2))];
        }
        {
            const int f = f0i + 2;
            const int c = f / SS, bn = f - c * SS;
            v.z = tile[bn * CCH + (c ^ ((((unsigned)bn >> 2) & 7u) << 2))];
        }
        {
            const int f = f0i + 3;
            const int c = f / SS, bn = f - c * SS;
            v.w = tile[bn * CCH + (c ^ ((((unsigned)bn >> 2) & 7u) << 2))];
        }
        *(float4*)(oreg + f0i) = v;
    }
}

extern "C" void kernel_launch(void* const* d_in, const int* in_sizes, int n_in,
                              void* d_out, int out_size, void* d_ws, size_t ws_size,
                              hipStream_t stream) {
    const float* fm2  = (const float*)d_in[0];
    const float* fm3  = (const float*)d_in[1];
    const float* fm4  = (const float*)d_in[2];
    const float* fm5  = (const float*)d_in[3];
    const float* rois = (const float*)d_in[4];
    float* out = (float*)d_out;

    roialign_kernel<<<BATCH * NROI, 448, 0, stream>>>(fm2, fm3, fm4, fm5, rois, out);
}

// Round 9
// 64.076 us; speedup vs baseline: 1.5778x; 1.5778x over previous
//
#include <hip/hip_runtime.h>

// ROIAlign (FPN, multi-level) for MI355X.
// Inputs (f32): fm2 [4,256,256,256] s4 | fm3 [4,128,128,256] s8
//               fm4 [4,64,64,256] s16  | fm5 [4,32,32,256] s32
//               rois [4,512,4] (x1,y1,x2,y2)
// Output (f32): [4,512,256,7,7]
//
// R8 -> R9: restore R6 (best: 64.3 us) after the cross-bin-cache regression
// (R8: serialized dependency chain across bins, 101 us). Two micro tweaks:
//  - no sched_barrier after the load batch (loads are batched by program
//    order; barrier was also blocking overlap of next-bin address math)
//  - 0.25 bin-average folded into merged row weights (4 fewer VALU/bin)
// Structure (proven): 1 ROI/block, 512 thr, scalar-guarded dedup'd float4
// gathers, LDS-staged XOR-swizzled tile, coalesced float4 writeback.

constexpr int S     = 7;
constexpr int SS    = 49;
constexpr int CCH   = 256;
constexpr int NROI  = 512;
constexpr int BATCH = 4;

__global__ __launch_bounds__(512, 4) void roialign_kernel(
    const float* __restrict__ fm2, const float* __restrict__ fm3,
    const float* __restrict__ fm4, const float* __restrict__ fm5,
    const float* __restrict__ rois, float* __restrict__ out)
{
    __shared__ float    tile[SS * CCH];   // 50176 B, XOR-swizzled channel index
    __shared__ float    s_wyh[14], s_wyl[14], s_wxh[14], s_wxl[14];
    __shared__ unsigned s_ry0[14], s_ry1[14], s_cx0[14], s_cx1[14];
    __shared__ float    s_bw[SS][4];      // merged row weights per bin (pre-scaled 0.25)
    __shared__ float    s_bu[SS][4];      // merged col weights per bin
    __shared__ unsigned s_bm[SS];         // survive mask: rows bits0-3, cols bits4-7

    const int roi = blockIdx.x;           // 0 .. B*N-1
    const int b   = roi >> 9;

    // ---- wave-uniform prologue ----
    const float x1  = rois[roi * 4 + 0];
    const float y1v = rois[roi * 4 + 1];
    const float x2  = rois[roi * 4 + 2];
    const float y2v = rois[roi * 4 + 3];

    const float area = (y2v - y1v) * (x2 - x1);
    const float lraw = logf(sqrtf(area) * (1.0f / 224.0f)) * 1.4426950408889634f + 4.0f;
    int lvl = (int)rintf(lraw);
    lvl = lvl < 2 ? 2 : (lvl > 5 ? 5 : lvl);

    const float* fm; int H; float scale;
    if (lvl == 2)      { fm = fm2; H = 256; scale = 0.25f;    }
    else if (lvl == 3) { fm = fm3; H = 128; scale = 0.125f;   }
    else if (lvl == 4) { fm = fm4; H = 64;  scale = 0.0625f;  }
    else               { fm = fm5; H = 32;  scale = 0.03125f; }
    const int W = H;
    fm += (size_t)b * H * W * CCH;

    const float bx1 = x1 * scale, by1 = y1v * scale;
    const float rw  = fmaxf(x2 * scale - bx1, 1.0f);
    const float rh  = fmaxf(y2v * scale - by1, 1.0f);
    const float stx = rw * (1.0f / 7.0f);
    const float sty = rh * (1.0f / 7.0f);

    const int t = threadIdx.x;

    // ---- sample LUT: 14 y entries (wave 0) + 14 x entries (wave 1) ----
    if (t < 14) {
        const int k = t;
        const float yy = by1 + ((float)k + 0.5f) * 0.5f * sty;
        const float Hf = (float)H;
        const bool  v  = (yy > -1.0f) && (yy < Hf);
        const float yc = fminf(fmaxf(yy, 0.0f), Hf - 1.0f);
        const int   y0 = (int)floorf(yc);
        const int   y1i = min(y0 + 1, H - 1);
        const float ly = yc - (float)y0;
        s_wyl[k] = v ? ly : 0.0f;
        s_wyh[k] = v ? 1.0f - ly : 0.0f;
        s_ry0[k] = (unsigned)(y0  * W * (CCH * 4));   // byte offset of fm row
        s_ry1[k] = (unsigned)(y1i * W * (CCH * 4));
    } else if (t >= 64 && t < 78) {
        const int k = t - 64;
        const float xx = bx1 + ((float)k + 0.5f) * 0.5f * stx;
        const float Wf = (float)W;
        const bool  v  = (xx > -1.0f) && (xx < Wf);
        const float xc = fminf(fmaxf(xx, 0.0f), Wf - 1.0f);
        const int   x0 = (int)floorf(xc);
        const int   x1i = min(x0 + 1, W - 1);
        const float lx = xc - (float)x0;
        s_wxl[k] = v ? lx : 0.0f;
        s_wxh[k] = v ? 1.0f - lx : 0.0f;
        s_cx0[k] = (unsigned)(x0  * (CCH * 4));       // byte offset of fm col
        s_cx1[k] = (unsigned)(x1i * (CCH * 4));
    }
    __syncthreads();

    // ---- per-bin merged weights + survive mask (one thread per bin) ----
    if (t < SS) {
        const int sy = t / 7, sx = t - sy * 7;
        const int ky = sy << 1, kx = sx << 1;

        float w0 = s_wyh[ky], w1 = s_wyl[ky], w2 = s_wyh[ky + 1], w3 = s_wyl[ky + 1];
        {
            const unsigned rA = s_ry0[ky], rB = s_ry1[ky];
            const unsigned rC = s_ry0[ky + 1], rD = s_ry1[ky + 1];
            const bool eBA = (rB == rA);
            if (eBA) { w0 += w1; w1 = 0.f; }
            const bool eCA = (rC == rA);
            const bool eCB = !eCA && (rC == rB);
            if (eCA) w0 += w2; else if (eCB) w1 += w2;
            if (eCA || eCB) w2 = 0.f;
            const bool eDA = (rD == rA);
            const bool eDB = !eDA && (rD == rB);
            const bool eDC = !eDA && !eDB && (rD == rC);
            if (eDA) w0 += w3; else if (eDB) w1 += w3; else if (eDC) w2 += w3;
            if (eDA || eDB || eDC) w3 = 0.f;
        }
        float u0 = s_wxh[kx], u1 = s_wxl[kx], u2 = s_wxh[kx + 1], u3 = s_wxl[kx + 1];
        {
            const unsigned cA = s_cx0[kx], cB = s_cx1[kx];
            const unsigned cC = s_cx0[kx + 1], cD = s_cx1[kx + 1];
            const bool eBA = (cB == cA);
            if (eBA) { u0 += u1; u1 = 0.f; }
            const bool eCA = (cC == cA);
            const bool eCB = !eCA && (cC == cB);
            if (eCA) u0 += u2; else if (eCB) u1 += u2;
            if (eCA || eCB) u2 = 0.f;
            const bool eDA = (cD == cA);
            const bool eDB = !eDA && (cD == cB);
            const bool eDC = !eDA && !eDB && (cD == cC);
            if (eDA) u0 += u3; else if (eDB) u1 += u3; else if (eDC) u2 += u3;
            if (eDA || eDB || eDC) u3 = 0.f;
        }
        // fold the 2x2 bin-average (0.25) into the row weights
        s_bw[t][0] = w0 * 0.25f; s_bw[t][1] = w1 * 0.25f;
        s_bw[t][2] = w2 * 0.25f; s_bw[t][3] = w3 * 0.25f;
        s_bu[t][0] = u0; s_bu[t][1] = u1; s_bu[t][2] = u2; s_bu[t][3] = u3;
        s_bm[t] = (w0 != 0.f ? 0x01u : 0u) | (w1 != 0.f ? 0x02u : 0u)
                | (w2 != 0.f ? 0x04u : 0u) | (w3 != 0.f ? 0x08u : 0u)
                | (u0 != 0.f ? 0x10u : 0u) | (u1 != 0.f ? 0x20u : 0u)
                | (u2 != 0.f ? 0x40u : 0u) | (u3 != 0.f ? 0x80u : 0u);
    }
    __syncthreads();

    // ---- compute: one bin per wave-pass, 4 channels (float4) per lane ----
    const int lane = t & 63;
    const int wv   = t >> 6;                       // 0..7
    const unsigned cb = (unsigned)(lane << 4);     // byte offset within pixel

    const char* __restrict__ fmb = (const char*)fm;
    const float4 z4 = make_float4(0.f, 0.f, 0.f, 0.f);

    for (int bin = wv; bin < SS; bin += 8) {
        const int sy = bin / 7;
        const int sx = bin - sy * 7;
        const int ky = sy << 1, kx = sx << 1;

        // scalar survive mask -> wave-uniform s_cbranch guards
        const unsigned m = (unsigned)__builtin_amdgcn_readfirstlane((int)s_bm[bin]);

        const float w0 = s_bw[bin][0], w1 = s_bw[bin][1];
        const float w2 = s_bw[bin][2], w3 = s_bw[bin][3];
        const float u0 = s_bu[bin][0], u1 = s_bu[bin][1];
        const float u2 = s_bu[bin][2], u3 = s_bu[bin][3];

        const unsigned rA = s_ry0[ky],     rB = s_ry1[ky];
        const unsigned rC = s_ry0[ky + 1], rD = s_ry1[ky + 1];
        const unsigned cA = s_cx0[kx],     cB = s_cx1[kx];
        const unsigned cC = s_cx0[kx + 1], cD = s_cx1[kx + 1];

#define LD4(OFF) (*(const float4*)(fmb + (OFF)))
        float4 f00 = z4, f01 = z4, f02 = z4, f03 = z4;
        float4 f10 = z4, f11 = z4, f12 = z4, f13 = z4;
        float4 f20 = z4, f21 = z4, f22 = z4, f23 = z4;
        float4 f30 = z4, f31 = z4, f32 = z4, f33 = z4;

        if ((m & 0x11u) == 0x11u) f00 = LD4(rA + cA + cb);
        if ((m & 0x21u) == 0x21u) f01 = LD4(rA + cB + cb);
        if ((m & 0x41u) == 0x41u) f02 = LD4(rA + cC + cb);
        if ((m & 0x81u) == 0x81u) f03 = LD4(rA + cD + cb);
        if ((m & 0x12u) == 0x12u) f10 = LD4(rB + cA + cb);
        if ((m & 0x22u) == 0x22u) f11 = LD4(rB + cB + cb);
        if ((m & 0x42u) == 0x42u) f12 = LD4(rB + cC + cb);
        if ((m & 0x82u) == 0x82u) f13 = LD4(rB + cD + cb);
        if ((m & 0x14u) == 0x14u) f20 = LD4(rC + cA + cb);
        if ((m & 0x24u) == 0x24u) f21 = LD4(rC + cB + cb);
        if ((m & 0x44u) == 0x44u) f22 = LD4(rC + cC + cb);
        if ((m & 0x84u) == 0x84u) f23 = LD4(rC + cD + cb);
        if ((m & 0x18u) == 0x18u) f30 = LD4(rD + cA + cb);
        if ((m & 0x28u) == 0x28u) f31 = LD4(rD + cB + cb);
        if ((m & 0x48u) == 0x48u) f32 = LD4(rD + cC + cb);
        if ((m & 0x88u) == 0x88u) f33 = LD4(rD + cD + cb);
#undef LD4

        float4 acc = z4;
#define ACC4(Wt, F) { const float pw_ = (Wt); \
        acc.x = fmaf(pw_, (F).x, acc.x); acc.y = fmaf(pw_, (F).y, acc.y); \
        acc.z = fmaf(pw_, (F).z, acc.z); acc.w = fmaf(pw_, (F).w, acc.w); }
        ACC4(w0 * u0, f00); ACC4(w0 * u1, f01); ACC4(w0 * u2, f02); ACC4(w0 * u3, f03);
        ACC4(w1 * u0, f10); ACC4(w1 * u1, f11); ACC4(w1 * u2, f12); ACC4(w1 * u3, f13);
        ACC4(w2 * u0, f20); ACC4(w2 * u1, f21); ACC4(w2 * u2, f22); ACC4(w2 * u3, f23);
        ACC4(w3 * u0, f30); ACC4(w3 * u1, f31); ACC4(w3 * u2, f32); ACC4(w3 * u3, f33);
#undef ACC4

        // tile[bin][c], channel index XOR-swizzled so the writeback's
        // (c fixed, bin varying) reads spread across banks.
        const unsigned xsw = (((unsigned)bin >> 2) & 7u) << 2;
        float* dst = &tile[bin * CCH + ((unsigned)(lane << 2) ^ xsw)];
        *(float4*)dst = acc;   // 0.25 already folded into row weights
    }

    __syncthreads();

    // ---- writeback: contiguous 256*49 floats, coalesced float4 stores ----
    float* oreg = out + (size_t)roi * (CCH * SS);
    for (int i = t; i < (CCH * SS) / 4; i += 512) {
        const int f0 = i * 4;
        float4 v;
        {
            const int f = f0 + 0;
            const int c = f / SS, bn = f - c * SS;
            v.x = tile[bn * CCH + (c ^ ((((unsigned)bn >> 2) & 7u) << 2))];
        }
        {
            const int f = f0 + 1;
            const int c = f / SS, bn = f - c * SS;
            v.y = tile[bn * CCH + (c ^ ((((unsigned)bn >> 2) & 7u) << 2))];
        }
        {
            const int f = f0 + 2;
            const int c = f / SS, bn = f - c * SS;
            v.z = tile[bn * CCH + (c ^ ((((unsigned)bn >> 2) & 7u) << 2))];
        }
        {
            const int f = f0 + 3;
            const int c = f / SS, bn = f - c * SS;
            v.w = tile[bn * CCH + (c ^ ((((unsigned)bn >> 2) & 7u) << 2))];
        }
        *(float4*)(oreg + f0) = v;
    }
}

extern "C" void kernel_launch(void* const* d_in, const int* in_sizes, int n_in,
                              void* d_out, int out_size, void* d_ws, size_t ws_size,
                              hipStream_t stream) {
    const float* fm2  = (const float*)d_in[0];
    const float* fm3  = (const float*)d_in[1];
    const float* fm4  = (const float*)d_in[2];
    const float* fm5  = (const float*)d_in[3];
    const float* rois = (const float*)d_in[4];
    float* out = (float*)d_out;

    roialign_kernel<<<BATCH * NROI, 512, 0, stream>>>(fm2, fm3, fm4, fm5, rois, out);
}